// Round 8
// baseline (131.034 us; speedup 1.0000x reference)
//
#include <hip/hip_runtime.h>
#include <float.h>
#include <math.h>

#define NB 8192      // batch
#define NC 128       // classes
#define NT 64        // time steps
#define ACE_EPS 1e-5f
#define FXSCALE 1048576.0f   // 2^20 fixed-point for deterministic integer mean

// workspace layout:
//   [0,    32KB)    prefix[NB] (int)
//   [32KB, 32KB+8)  acc        (unsigned long long)
//   [32KB+8, +12)   ticket     (unsigned int)

// ---------------------------------------------------------------------------
// 0) exclusive prefix sum of target_lengths + zero acc/ticket. 1 block, ~3us.
// ---------------------------------------------------------------------------
__global__ __launch_bounds__(256) void prefix_kernel(
    const int* __restrict__ lens, int* __restrict__ prefix,
    unsigned long long* __restrict__ acc, unsigned int* __restrict__ ticket) {
  if (threadIdx.x == 0) { *acc = 0ull; *ticket = 0u; }
  const int tid = threadIdx.x;
  const int lane = tid & 63;
  const int wid = tid >> 6;

  int4 v[8];
  const int4* l4 = (const int4*)lens + tid * 8;   // 32 ints per thread
#pragma unroll
  for (int i = 0; i < 8; ++i) v[i] = l4[i];
  int s = 0;
#pragma unroll
  for (int i = 0; i < 8; ++i) s += v[i].x + v[i].y + v[i].z + v[i].w;

  int scan = s;
#pragma unroll
  for (int off = 1; off < 64; off <<= 1) {
    int t = __shfl_up(scan, off, 64);
    if (lane >= off) scan += t;
  }
  __shared__ int wsum[4];
  if (lane == 63) wsum[wid] = scan;
  __syncthreads();
  int wbase = 0;
  for (int w = 0; w < wid; ++w) wbase += wsum[w];

  int run = wbase + scan - s;
  int4 o[8];
#pragma unroll
  for (int i = 0; i < 8; ++i) {
    const int a = run;
    const int b2 = a + v[i].x;
    const int c2 = b2 + v[i].y;
    const int d2 = c2 + v[i].z;
    o[i] = make_int4(a, b2, c2, d2);
    run = d2 + v[i].w;
  }
  int4* p4 = (int4*)prefix + tid * 8;
#pragma unroll
  for (int i = 0; i < 8; ++i) p4[i] = o[i];
}

// ---------------------------------------------------------------------------
// A) fused streaming argmax + ACE loss + deterministic fixed-point mean.
//    One wave per sample, 4 samples per 256-thread block, grid = 2048.
//    Hot loop: hand-pipelined 8-stage rotating float4 buffer (forces 8 loads
//    in flight; collapse-proof vs allocator, proven R7). Lane mapping:
//    tg=lane&15 (t=4tg..4tg+3), crow=lane>>4 (c=4*cc+crow).
//    Tail: ballot/popcount loss (lane l owns t=4*(l&15)+(l>>4), a bijection),
//    block-sum of 4 wave losses via 16B LDS, ONE u64 fixed-point atomicAdd
//    per block + acq_rel ticket; ticket winner writes the mean.
//    Integer adds are order-independent -> bit-deterministic across replays.
// ---------------------------------------------------------------------------
__global__ __launch_bounds__(256, 8) void ace_fused_kernel(
    const float* __restrict__ x, const int* __restrict__ y,
    const int* __restrict__ lens, const int* __restrict__ prefix,
    unsigned long long* __restrict__ acc, unsigned int* __restrict__ ticket,
    float* __restrict__ out) {
  const int wave = threadIdx.x >> 6;
  const int lane = threadIdx.x & 63;
  const int b = blockIdx.x * 4 + wave;
  const int crow = lane >> 4;

  const float4* xv = (const float4*)(x + (size_t)b * (NC * NT)) + lane;

  float mv[4];
  int am[4];
#pragma unroll
  for (int j = 0; j < 4; ++j) { mv[j] = -FLT_MAX; am[j] = 0; }

  // ---- 8-stage software pipeline over 32 float4 loads ----
  float4 p0 = xv[0 * 64], p1 = xv[1 * 64], p2 = xv[2 * 64], p3 = xv[3 * 64];
  float4 p4 = xv[4 * 64], p5 = xv[5 * 64], p6 = xv[6 * 64], p7 = xv[7 * 64];

#define CONSUME(P, CC)                                                       \
  {                                                                          \
    const int c = (CC) * 4 + crow;                                           \
    if (P.x > mv[0]) { mv[0] = P.x; am[0] = c; }                             \
    if (P.y > mv[1]) { mv[1] = P.y; am[1] = c; }                             \
    if (P.z > mv[2]) { mv[2] = P.z; am[2] = c; }                             \
    if (P.w > mv[3]) { mv[3] = P.w; am[3] = c; }                             \
  }

#pragma unroll
  for (int base = 0; base < 32; base += 8) {
    CONSUME(p0, base + 0); if (base + 8 < 32) p0 = xv[(base + 8) * 64];
    CONSUME(p1, base + 1); if (base + 9 < 32) p1 = xv[(base + 9) * 64];
    CONSUME(p2, base + 2); if (base + 10 < 32) p2 = xv[(base + 10) * 64];
    CONSUME(p3, base + 3); if (base + 11 < 32) p3 = xv[(base + 11) * 64];
    CONSUME(p4, base + 4); if (base + 12 < 32) p4 = xv[(base + 12) * 64];
    CONSUME(p5, base + 5); if (base + 13 < 32) p5 = xv[(base + 13) * 64];
    CONSUME(p6, base + 6); if (base + 14 < 32) p6 = xv[(base + 14) * 64];
    CONSUME(p7, base + 7); if (base + 15 < 32) p7 = xv[(base + 15) * 64];
  }
#undef CONSUME

  // combine across the 4 lanes (crow dim) sharing one t-group; min idx on tie
#pragma unroll
  for (int j = 0; j < 4; ++j) {
#pragma unroll
    for (int off = 16; off < 64; off <<= 1) {
      float om = __shfl_xor(mv[j], off, 64);
      int oa = __shfl_xor(am[j], off, 64);
      if (om > mv[j] || (om == mv[j] && oa < am[j])) { mv[j] = om; am[j] = oa; }
    }
  }
  int my_am = am[0];
  if (crow == 1) my_am = am[1];
  if (crow == 2) my_am = am[2];
  if (crow == 3) my_am = am[3];

  // ---- ballot/popcount loss tail ----
  const int len = lens[b];
  const int start = prefix[b];
  const int yv = (lane < len) ? y[start + lane] : -1;

  int ns = 0;
  for (int i = 0; i < len; ++i) {
    const int c = __shfl(yv, i, 64);
    const unsigned long long baly = __ballot(lane < len && yv == c);
    const int nkc = __popcll(__ballot(my_am == c));
    if ((int)__ffsll(baly) - 1 == i) ns += nkc;   // uniform: first occurrence
  }
  const float inv_ns = (ns > 0) ? (1.0f / (float)ns) : 0.0f;
  const float inv_ys = 1.0f / (float)len;         // y_sum == len
  float a = 0.0f;
  for (int i = 0; i < len; ++i) {
    const int c = __shfl(yv, i, 64);
    const unsigned long long baly = __ballot(lane < len && yv == c);
    if ((int)__ffsll(baly) - 1 == i) {            // uniform branch
      const int nkc = __popcll(__ballot(my_am == c));
      const int ykc = __popcll(baly);
      const float np = (ns == 0) ? ACE_EPS : fmaxf((float)nkc * inv_ns, ACE_EPS);
      a -= np * logf((float)ykc * inv_ys);
    }
  }

  // ---- block aggregation + one fixed-point atomic per block ----
  __shared__ float wloss[4];
  if (lane == 0) wloss[wave] = a;
  __syncthreads();
  if (threadIdx.x == 0) {
    const float bl = wloss[0] + wloss[1] + wloss[2] + wloss[3];
    const long long fx = (long long)llrintf(bl * FXSCALE);
    __hip_atomic_fetch_add(acc, (unsigned long long)fx,
                           __ATOMIC_ACQ_REL, __HIP_MEMORY_SCOPE_AGENT);
    const unsigned int done = __hip_atomic_fetch_add(
        ticket, 1u, __ATOMIC_ACQ_REL, __HIP_MEMORY_SCOPE_AGENT);
    if (done == (unsigned int)(gridDim.x - 1)) {
      const unsigned long long tot = __hip_atomic_load(
          acc, __ATOMIC_ACQUIRE, __HIP_MEMORY_SCOPE_AGENT);
      out[0] = (float)((double)(long long)tot *
                       (1.0 / (double)FXSCALE) / (double)NB);
    }
  }
}

extern "C" void kernel_launch(void* const* d_in, const int* in_sizes, int n_in,
                              void* d_out, int out_size, void* d_ws, size_t ws_size,
                              hipStream_t stream) {
  const float* x = (const float*)d_in[0];          // [B, C, T] f32
  const int* y = (const int*)d_in[1];              // [B*L] i32
  const int* lens = (const int*)d_in[2];           // [B] i32
  float* out = (float*)d_out;                      // scalar f32

  int* prefix = (int*)d_ws;                                          // 32 KB
  unsigned long long* acc = (unsigned long long*)((char*)d_ws + 32 * 1024);
  unsigned int* ticket = (unsigned int*)((char*)d_ws + 32 * 1024 + 8);

  prefix_kernel<<<1, 256, 0, stream>>>(lens, prefix, acc, ticket);
  ace_fused_kernel<<<NB / 4, 256, 0, stream>>>(x, y, lens, prefix, acc,
                                               ticket, out);
}

// Round 9
// 56.176 us; speedup vs baseline: 2.3325x; 2.3325x over previous
//
#include <hip/hip_runtime.h>
#include <float.h>
#include <math.h>

#define NB 8192      // batch
#define NC 128       // classes
#define NT 64        // time steps
#define ACE_EPS 1e-5f

// workspace layout:
//   [0,    32KB)   prefix[NB] (int)
//   [32KB, 64KB)   loss[NB]   (float)

// ---------------------------------------------------------------------------
// 0) exclusive prefix sum of target_lengths — single 1024-thread block.
//    8 ints per thread, shuffle scan + cross-wave LDS combine. ~1.5 us.
// ---------------------------------------------------------------------------
__global__ __launch_bounds__(1024) void prefix_kernel(
    const int* __restrict__ lens, int* __restrict__ prefix) {
  const int tid = threadIdx.x;
  const int lane = tid & 63;
  const int wid = tid >> 6;          // 16 waves

  int4 v[2];
  const int4* l4 = (const int4*)lens + tid * 2;   // 8 ints per thread
  v[0] = l4[0]; v[1] = l4[1];
  const int s = v[0].x + v[0].y + v[0].z + v[0].w +
                v[1].x + v[1].y + v[1].z + v[1].w;

  int scan = s;
#pragma unroll
  for (int off = 1; off < 64; off <<= 1) {
    int t = __shfl_up(scan, off, 64);
    if (lane >= off) scan += t;
  }
  __shared__ int wsum[16];
  if (lane == 63) wsum[wid] = scan;
  __syncthreads();
  int wbase = 0;
  for (int w = 0; w < wid; ++w) wbase += wsum[w];

  int run = wbase + scan - s;        // exclusive prefix of this thread's 8
  int4 o[2];
#pragma unroll
  for (int i = 0; i < 2; ++i) {
    const int a = run;
    const int b2 = a + v[i].x;
    const int c2 = b2 + v[i].y;
    const int d2 = c2 + v[i].z;
    o[i] = make_int4(a, b2, c2, d2);
    run = d2 + v[i].w;
  }
  int4* p4 = (int4*)prefix + tid * 2;
  p4[0] = o[0]; p4[1] = o[1];
}

// ---------------------------------------------------------------------------
// A) fused streaming argmax + ACE loss (R5 structure — no LDS, no atomics,
//    no barrier: kernels with barrier/atomic tails collapse to 32 VGPR and
//    serialize the stream; R2/R6/R8 evidence).
//    One wave per sample, 4 samples per 256-thread block.
//    Lane mapping: tg=lane&15 (t=4tg..4tg+3), crow=lane>>4 (c=4*cc+crow);
//    wave reads 1 KiB contiguous per load instruction.
//    R9 change: tail loads (lens/prefix/y) hoisted BEFORE the stream so
//    their latency hides under the 32 float4 loads.
// ---------------------------------------------------------------------------
__global__ __launch_bounds__(256, 8) void ace_fused_kernel(
    const float* __restrict__ x, const int* __restrict__ y,
    const int* __restrict__ lens, const int* __restrict__ prefix,
    float* __restrict__ loss_out) {
  const int wave = threadIdx.x >> 6;
  const int lane = threadIdx.x & 63;
  const int b = blockIdx.x * 4 + wave;
  const int crow = lane >> 4;

  // ---- hoisted tail inputs (latency hides under the x stream) ----
  const int len = lens[b];
  const int start = prefix[b];
  const int yv = (lane < len) ? y[start + lane] : -1;

  // ---- streaming argmax: 32 coalesced float4 loads, unroll-8 pipeline ----
  const float4* xv = (const float4*)(x + (size_t)b * (NC * NT));
  float mv[4];
  int am[4];
#pragma unroll
  for (int j = 0; j < 4; ++j) { mv[j] = -FLT_MAX; am[j] = 0; }

#pragma unroll 8
  for (int cc = 0; cc < 32; ++cc) {
    const int c = cc * 4 + crow;
    float4 v = xv[cc * 64 + lane];
    float vv[4] = {v.x, v.y, v.z, v.w};
#pragma unroll
    for (int j = 0; j < 4; ++j) {
      if (vv[j] > mv[j]) { mv[j] = vv[j]; am[j] = c; }   // strict > : first max
    }
  }

  // combine across the 4 lanes (crow dim) sharing one t-group; min idx on tie
#pragma unroll
  for (int j = 0; j < 4; ++j) {
#pragma unroll
    for (int off = 16; off < 64; off <<= 1) {
      float om = __shfl_xor(mv[j], off, 64);
      int oa = __shfl_xor(am[j], off, 64);
      if (om > mv[j] || (om == mv[j] && oa < am[j])) { mv[j] = om; am[j] = oa; }
    }
  }
  int my_am = am[0];
  if (crow == 1) my_am = am[1];
  if (crow == 2) my_am = am[2];
  if (crow == 3) my_am = am[3];

  // ---- ballot/popcount loss tail (lane l owns t = 4*(l&15)+(l>>4)) ----
  int ns = 0;
  for (int i = 0; i < len; ++i) {
    const int c = __shfl(yv, i, 64);
    const unsigned long long baly = __ballot(lane < len && yv == c);
    const int nkc = __popcll(__ballot(my_am == c));
    if ((int)__ffsll(baly) - 1 == i) ns += nkc;   // uniform: first occurrence
  }
  const float inv_ns = (ns > 0) ? (1.0f / (float)ns) : 0.0f;
  const float inv_ys = 1.0f / (float)len;         // y_sum == len
  float a = 0.0f;
  for (int i = 0; i < len; ++i) {
    const int c = __shfl(yv, i, 64);
    const unsigned long long baly = __ballot(lane < len && yv == c);
    if ((int)__ffsll(baly) - 1 == i) {            // uniform branch
      const int nkc = __popcll(__ballot(my_am == c));
      const int ykc = __popcll(baly);
      const float np = (ns == 0) ? ACE_EPS : fmaxf((float)nkc * inv_ns, ACE_EPS);
      a -= np * logf((float)ykc * inv_ys);
    }
  }
  if (lane == 0) loss_out[b] = a;
}

// ---------------------------------------------------------------------------
// C) deterministic mean over B per-sample losses — single 1024-thread block
// ---------------------------------------------------------------------------
__global__ void reduce_kernel(const float* __restrict__ loss,
                              float* __restrict__ out) {
  __shared__ float s[1024];
  float a = 0.0f;
  for (int i = threadIdx.x; i < NB; i += 1024) a += loss[i];
  s[threadIdx.x] = a;
  __syncthreads();
  for (int off = 512; off > 0; off >>= 1) {
    if ((int)threadIdx.x < off) s[threadIdx.x] += s[threadIdx.x + off];
    __syncthreads();
  }
  if (threadIdx.x == 0) out[0] = s[0] / (float)NB;
}

extern "C" void kernel_launch(void* const* d_in, const int* in_sizes, int n_in,
                              void* d_out, int out_size, void* d_ws, size_t ws_size,
                              hipStream_t stream) {
  const float* x = (const float*)d_in[0];          // [B, C, T] f32
  const int* y = (const int*)d_in[1];              // [B*L] i32
  const int* lens = (const int*)d_in[2];           // [B] i32
  float* out = (float*)d_out;                      // scalar f32

  int* prefix = (int*)d_ws;                                      // 32 KB
  float* loss = (float*)((char*)d_ws + 32 * 1024);               // 32 KB

  prefix_kernel<<<1, 1024, 0, stream>>>(lens, prefix);
  ace_fused_kernel<<<NB / 4, 256, 0, stream>>>(x, y, lens, prefix, loss);
  reduce_kernel<<<1, 1024, 0, stream>>>(loss, out);
}

// Round 10
// 54.567 us; speedup vs baseline: 2.4013x; 1.0295x over previous
//
#include <hip/hip_runtime.h>
#include <float.h>
#include <math.h>

#define NB 8192      // batch
#define NC 128       // classes
#define NT 64        // time steps
#define ACE_EPS 1e-5f

// workspace layout:
//   [0,    32KB)   prefix[NB] (int)
//   [32KB, 64KB)   loss[NB]   (float)

// ---------------------------------------------------------------------------
// 0) exclusive prefix sum of target_lengths — single 1024-thread block.
//    8 ints per thread, shuffle scan + cross-wave LDS combine. ~1.5 us.
// ---------------------------------------------------------------------------
__global__ __launch_bounds__(1024) void prefix_kernel(
    const int* __restrict__ lens, int* __restrict__ prefix) {
  const int tid = threadIdx.x;
  const int lane = tid & 63;
  const int wid = tid >> 6;          // 16 waves

  int4 v[2];
  const int4* l4 = (const int4*)lens + tid * 2;   // 8 ints per thread
  v[0] = l4[0]; v[1] = l4[1];
  const int s = v[0].x + v[0].y + v[0].z + v[0].w +
                v[1].x + v[1].y + v[1].z + v[1].w;

  int scan = s;
#pragma unroll
  for (int off = 1; off < 64; off <<= 1) {
    int t = __shfl_up(scan, off, 64);
    if (lane >= off) scan += t;
  }
  __shared__ int wsum[16];
  if (lane == 63) wsum[wid] = scan;
  __syncthreads();
  int wbase = 0;
  for (int w = 0; w < wid; ++w) wbase += wsum[w];

  int run = wbase + scan - s;        // exclusive prefix of this thread's 8
  int4 o[2];
#pragma unroll
  for (int i = 0; i < 2; ++i) {
    const int a = run;
    const int b2 = a + v[i].x;
    const int c2 = b2 + v[i].y;
    const int d2 = c2 + v[i].z;
    o[i] = make_int4(a, b2, c2, d2);
    run = d2 + v[i].w;
  }
  int4* p4 = (int4*)prefix + tid * 2;
  p4[0] = o[0]; p4[1] = o[1];
}

// ---------------------------------------------------------------------------
// A) fused streaming argmax + ACE loss (proven R9 configuration — no LDS,
//    no atomics, no barrier in this kernel: barrier/atomic tails collapse
//    the allocation to 32 VGPR and serialize the stream; R2/R6/R8 evidence).
//    One wave per sample, 4 samples per 256-thread block.
//    Lane mapping: tg=lane&15 (t=4tg..4tg+3), crow=lane>>4 (c=4*cc+crow);
//    wave reads 1 KiB contiguous per load instruction. Tail inputs hoisted
//    before the stream so their latency hides under the 32 float4 loads.
// ---------------------------------------------------------------------------
__global__ __launch_bounds__(256, 8) void ace_fused_kernel(
    const float* __restrict__ x, const int* __restrict__ y,
    const int* __restrict__ lens, const int* __restrict__ prefix,
    float* __restrict__ loss_out) {
  const int wave = threadIdx.x >> 6;
  const int lane = threadIdx.x & 63;
  const int b = blockIdx.x * 4 + wave;
  const int crow = lane >> 4;

  // ---- hoisted tail inputs (latency hides under the x stream) ----
  const int len = lens[b];
  const int start = prefix[b];
  const int yv = (lane < len) ? y[start + lane] : -1;

  // ---- streaming argmax: 32 coalesced float4 loads, unroll-8 pipeline ----
  const float4* xv = (const float4*)(x + (size_t)b * (NC * NT));
  float mv[4];
  int am[4];
#pragma unroll
  for (int j = 0; j < 4; ++j) { mv[j] = -FLT_MAX; am[j] = 0; }

#pragma unroll 8
  for (int cc = 0; cc < 32; ++cc) {
    const int c = cc * 4 + crow;
    float4 v = xv[cc * 64 + lane];
    float vv[4] = {v.x, v.y, v.z, v.w};
#pragma unroll
    for (int j = 0; j < 4; ++j) {
      if (vv[j] > mv[j]) { mv[j] = vv[j]; am[j] = c; }   // strict > : first max
    }
  }

  // combine across the 4 lanes (crow dim) sharing one t-group; min idx on tie
#pragma unroll
  for (int j = 0; j < 4; ++j) {
#pragma unroll
    for (int off = 16; off < 64; off <<= 1) {
      float om = __shfl_xor(mv[j], off, 64);
      int oa = __shfl_xor(am[j], off, 64);
      if (om > mv[j] || (om == mv[j] && oa < am[j])) { mv[j] = om; am[j] = oa; }
    }
  }
  int my_am = am[0];
  if (crow == 1) my_am = am[1];
  if (crow == 2) my_am = am[2];
  if (crow == 3) my_am = am[3];

  // ---- ballot/popcount loss tail (lane l owns t = 4*(l&15)+(l>>4)) ----
  int ns = 0;
  for (int i = 0; i < len; ++i) {
    const int c = __shfl(yv, i, 64);
    const unsigned long long baly = __ballot(lane < len && yv == c);
    const int nkc = __popcll(__ballot(my_am == c));
    if ((int)__ffsll(baly) - 1 == i) ns += nkc;   // uniform: first occurrence
  }
  const float inv_ns = (ns > 0) ? (1.0f / (float)ns) : 0.0f;
  const float inv_ys = 1.0f / (float)len;         // y_sum == len
  float a = 0.0f;
  for (int i = 0; i < len; ++i) {
    const int c = __shfl(yv, i, 64);
    const unsigned long long baly = __ballot(lane < len && yv == c);
    if ((int)__ffsll(baly) - 1 == i) {            // uniform branch
      const int nkc = __popcll(__ballot(my_am == c));
      const int ykc = __popcll(baly);
      const float np = (ns == 0) ? ACE_EPS : fmaxf((float)nkc * inv_ns, ACE_EPS);
      a -= np * logf((float)ykc * inv_ys);
    }
  }
  if (lane == 0) loss_out[b] = a;
}

// ---------------------------------------------------------------------------
// C) deterministic mean — single 512-thread block, float4 loads,
//    shuffle-reduce (2 syncs instead of 10). Fixed order -> deterministic.
// ---------------------------------------------------------------------------
__global__ __launch_bounds__(512) void reduce_kernel(
    const float* __restrict__ loss, float* __restrict__ out) {
  const int tid = threadIdx.x;
  const int lane = tid & 63;
  const int wid = tid >> 6;          // 8 waves
  const float4* l4 = (const float4*)loss;   // 2048 float4

  float a = 0.0f;
#pragma unroll
  for (int i = 0; i < 4; ++i) {
    float4 v = l4[tid + i * 512];
    a += v.x + v.y + v.z + v.w;
  }
#pragma unroll
  for (int off = 1; off < 64; off <<= 1) a += __shfl_xor(a, off, 64);

  __shared__ float ws[8];
  if (lane == 0) ws[wid] = a;
  __syncthreads();
  if (tid == 0) {
    float s = 0.0f;
#pragma unroll
    for (int w = 0; w < 8; ++w) s += ws[w];
    out[0] = s / (float)NB;
  }
}

extern "C" void kernel_launch(void* const* d_in, const int* in_sizes, int n_in,
                              void* d_out, int out_size, void* d_ws, size_t ws_size,
                              hipStream_t stream) {
  const float* x = (const float*)d_in[0];          // [B, C, T] f32
  const int* y = (const int*)d_in[1];              // [B*L] i32
  const int* lens = (const int*)d_in[2];           // [B] i32
  float* out = (float*)d_out;                      // scalar f32

  int* prefix = (int*)d_ws;                                      // 32 KB
  float* loss = (float*)((char*)d_ws + 32 * 1024);               // 32 KB

  prefix_kernel<<<1, 1024, 0, stream>>>(lens, prefix);
  ace_fused_kernel<<<NB / 4, 256, 0, stream>>>(x, y, lens, prefix, loss);
  reduce_kernel<<<1, 512, 0, stream>>>(loss, out);
}